// Round 3
// baseline (386.224 us; speedup 1.0000x reference)
//
#include <hip/hip_runtime.h>
#include <math.h>

#define N_SEQ 1024
#define LL 64
#define DH 256
#define DX 128
#define MQ 8192
#define GG 4096
#define NTYP 64
#define NMEM 262144

// ---------------- counting-sort based segment sum ---------------------------
__global__ __launch_bounds__(256) void k_hist(const int* __restrict__ grp,
                                              int* __restrict__ cnt) {
    int i = blockIdx.x * 256 + threadIdx.x;
    if (i < NMEM) atomicAdd(&cnt[grp[i]], 1);
}

// single block, 1024 threads, 4 counts per thread -> exclusive scan
__global__ __launch_bounds__(1024) void k_scan(const int* __restrict__ cnt,
                                               int* __restrict__ ofs,
                                               int* __restrict__ cur) {
    __shared__ int wsum[16];
    int tid = threadIdx.x;
    int4 c = ((const int4*)cnt)[tid];
    int local = c.x + c.y + c.z + c.w;
    int lane = tid & 63, w = tid >> 6;
    int v = local;
    for (int off = 1; off < 64; off <<= 1) {
        int t = __shfl_up(v, off);
        if (lane >= off) v += t;
    }
    if (lane == 63) wsum[w] = v;
    __syncthreads();
    if (tid < 16) {
        int s = wsum[tid];
        for (int off = 1; off < 16; off <<= 1) {
            int t = __shfl_up(s, off);
            if (tid >= off) s += t;
        }
        wsum[tid] = s;
    }
    __syncthreads();
    int base = (w > 0 ? wsum[w - 1] : 0) + (v - local);
    int4 o;
    o.x = base;
    o.y = base + c.x;
    o.z = o.y + c.y;
    o.w = o.z + c.z;
    ((int4*)ofs)[tid] = o;
    ((int4*)cur)[tid] = o;
}

__global__ __launch_bounds__(256) void k_permute(const int* __restrict__ grp,
                                                 const int* __restrict__ mem,
                                                 int* __restrict__ cur,
                                                 int* __restrict__ tok_sorted) {
    int i = blockIdx.x * 256 + threadIdx.x;
    if (i < NMEM) {
        int g = grp[i];
        int pos = atomicAdd(&cur[g], 1);
        tok_sorted[pos] = mem[i];
    }
}

// one block (128 threads) per group: z[g] = sum of tok_emb rows
__global__ __launch_bounds__(128) void k_zsum(const int* __restrict__ ofs,
                                              const int* __restrict__ cnt,
                                              const int* __restrict__ tok_sorted,
                                              const float* __restrict__ tok_emb,
                                              float* __restrict__ z) {
    __shared__ int idxs[128];
    int g = blockIdx.x;
    int tid = threadIdx.x;
    int start = ofs[g], n = cnt[g];
    float acc = 0.f;
    for (int j0 = 0; j0 < n; j0 += 128) {
        __syncthreads();
        int rem = n - j0;
        if (tid < rem) idxs[tid] = tok_sorted[start + j0 + tid];
        __syncthreads();
        int kmax = rem < 128 ? rem : 128;
        for (int k = 0; k < kmax; ++k)
            acc += tok_emb[(size_t)idxs[k] * DX + tid];
    }
    z[(size_t)g * DX + tid] = acc;
}

// ---------------- per-n query ranges (idx is sorted) ------------------------
__global__ __launch_bounds__(1024) void k_ranges(const int* __restrict__ idx,
                                                 int* __restrict__ ofs_n) {
    int n = threadIdx.x;
    int lo = 0, hi = MQ;
    while (lo < hi) {
        int mid = (lo + hi) >> 1;
        if (idx[mid] < n) lo = mid + 1; else hi = mid;
    }
    ofs_n[n] = lo;
    if (n == 0) ofs_n[N_SEQ] = MQ;
}

// ---------------- transpose Wk (256x256) -> WkT[e*256+d] = Wk[d*256+e] ------
__global__ void k_transpose(const float* __restrict__ Wk, float* __restrict__ WkT) {
    __shared__ float tile[32][33];
    int tx = threadIdx.x, ty = threadIdx.y;
    int bx = blockIdx.x, by = blockIdx.y;
    tile[ty][tx] = Wk[(size_t)(by * 32 + ty) * 256 + bx * 32 + tx];
    __syncthreads();
    WkT[(size_t)(bx * 32 + ty) * 256 + by * 32 + tx] = tile[tx][ty];
}

// ---------------- Wqk[j,d] = Wq[j,:]·Wk[d,:]; wqb[j]=Wq[j,:]·bk;
//                  bqk[d] = bq·Wk[d,:]; sqb = bq·bk --------------------------
__global__ __launch_bounds__(256) void k_wqk(const float* __restrict__ Wq,
                                             const float* __restrict__ bq,
                                             const float* __restrict__ bk,
                                             const float* __restrict__ WkT,
                                             float* __restrict__ Wqk,
                                             float* __restrict__ wqb,
                                             float* __restrict__ bqk,
                                             float* __restrict__ sqb) {
    __shared__ float row[256];
    __shared__ float red[4];
    int j = blockIdx.x;
    int tid = threadIdx.x;
    if (j < 512) {
        row[tid] = Wq[(size_t)j * 256 + tid];
        __syncthreads();
        float acc = 0.f;
#pragma unroll 4
        for (int e = 0; e < 256; ++e) acc += row[e] * WkT[(size_t)e * 256 + tid];
        Wqk[(size_t)j * 256 + tid] = acc;
        float p = row[tid] * bk[tid];
        for (int o = 32; o; o >>= 1) p += __shfl_xor(p, o);
        if ((tid & 63) == 0) red[tid >> 6] = p;
        __syncthreads();
        if (tid == 0) wqb[j] = red[0] + red[1] + red[2] + red[3];
    } else {
        float acc = 0.f;
#pragma unroll 4
        for (int e = 0; e < 256; ++e) acc += bq[e] * WkT[(size_t)e * 256 + tid];
        bqk[tid] = acc;
        float p = bq[tid] * bk[tid];
        for (int o = 32; o; o >>= 1) p += __shfl_xor(p, o);
        if ((tid & 63) == 0) red[tid >> 6] = p;
        __syncthreads();
        if (tid == 0) sqb[0] = red[0] + red[1] + red[2] + red[3];
    }
}

// ---------------- qk[m] = qcat@Wqk + bqk ; qb[m] = qcat·wqb + sqb -----------
#define TMQ 16
__global__ __launch_bounds__(256) void k_qk2(const float* __restrict__ h_grp,
                                             const int* __restrict__ idx,
                                             const int* __restrict__ srcv,
                                             const int* __restrict__ dstv,
                                             const float* __restrict__ Wqk,
                                             const float* __restrict__ bqk,
                                             const float* __restrict__ wqb,
                                             const float* __restrict__ sqb,
                                             float* __restrict__ qk,
                                             float* __restrict__ qb) {
    __shared__ __align__(16) float qs[TMQ][512];
    __shared__ float part[TMQ][16];
    int m0 = blockIdx.x * TMQ;
    int tid = threadIdx.x;
    for (int mm = 0; mm < TMQ; ++mm) {
        int m = m0 + mm;
        int n = idx[m], s = srcv[m], d = dstv[m];
        qs[mm][tid]       = h_grp[((size_t)n * LL + s) * DH + tid];
        qs[mm][256 + tid] = h_grp[((size_t)n * LL + d) * DH + tid];
    }
    __syncthreads();
    float acc[TMQ];
    float b = bqk[tid];
#pragma unroll
    for (int mm = 0; mm < TMQ; ++mm) acc[mm] = b;
    for (int j4 = 0; j4 < 128; ++j4) {
        float w0 = Wqk[(size_t)(j4 * 4 + 0) * 256 + tid];
        float w1 = Wqk[(size_t)(j4 * 4 + 1) * 256 + tid];
        float w2 = Wqk[(size_t)(j4 * 4 + 2) * 256 + tid];
        float w3 = Wqk[(size_t)(j4 * 4 + 3) * 256 + tid];
#pragma unroll
        for (int mm = 0; mm < TMQ; ++mm) {
            float4 qv = ((const float4*)qs[mm])[j4];
            acc[mm] += qv.x * w0 + qv.y * w1 + qv.z * w2 + qv.w * w3;
        }
    }
    for (int mm = 0; mm < TMQ; ++mm)
        qk[(size_t)(m0 + mm) * 256 + tid] = acc[mm];
    // qb: per-m dot(qcat, wqb) + sqb
    {
        int mm = tid >> 4, seg = tid & 15;
        float p = 0.f;
        for (int j = seg * 32; j < seg * 32 + 32; ++j)
            p += qs[mm][j] * wqb[j];
        part[mm][seg] = p;
    }
    __syncthreads();
    if (tid < TMQ) {
        float s = sqb[0];
        for (int k = 0; k < 16; ++k) s += part[tid][k];
        qb[m0 + tid] = s;
    }
}

// ---------------- per-n attention: scores -> softmax -> ctx -----------------
__global__ __launch_bounds__(256) void k_attn2(const float* __restrict__ h_grp,
                                               const int* __restrict__ pos2grp,
                                               const int* __restrict__ msk,
                                               const float* __restrict__ z,
                                               const float* __restrict__ qk,
                                               const float* __restrict__ qb,
                                               const int* __restrict__ ofs_n,
                                               float* __restrict__ ctx) {
    int n = blockIdx.x;
    int start = ofs_n[n], end = ofs_n[n + 1];
    if (start >= end) return;
    __shared__ __align__(16) float hs[LL * DH];
    __shared__ float attn_s[LL];
    __shared__ int grp_s[LL];
    __shared__ int msk_s[LL];
    int tid = threadIdx.x, lane = tid & 63, w = tid >> 6;
    const float4* hg4 = (const float4*)(h_grp + (size_t)n * LL * DH);
    float4* hs4 = (float4*)hs;
#pragma unroll
    for (int it = 0; it < 16; ++it) hs4[tid + it * 256] = hg4[tid + it * 256];
    if (tid < LL) {
        grp_s[tid] = pos2grp[n * LL + tid];
        msk_s[tid] = msk[n * LL + tid];
    }
    __syncthreads();
    for (int m = start; m < end; ++m) {
        float4 qv = ((const float4*)(qk + (size_t)m * 256))[lane];
        float qbv = qb[m];
#pragma unroll
        for (int i = 0; i < 16; ++i) {
            int l = w * 16 + i;
            float4 hv = ((const float4*)(hs + l * 256))[lane];
            float p = hv.x * qv.x + hv.y * qv.y + hv.z * qv.z + hv.w * qv.w;
            for (int o = 32; o; o >>= 1) p += __shfl_xor(p, o);
            if (lane == 0)
                attn_s[l] = msk_s[l] ? (p + qbv) * (1.0f / 16.0f) : -INFINITY;
        }
        __syncthreads();
        if (tid < LL) {
            float s = attn_s[tid];
            float mx = s;
            for (int o = 32; o; o >>= 1) mx = fmaxf(mx, __shfl_xor(mx, o));
            float p = __expf(s - mx);
            float sum = p;
            for (int o = 32; o; o >>= 1) sum += __shfl_xor(sum, o);
            attn_s[tid] = p / sum;
        }
        __syncthreads();
        if (tid < DX) {
            float acc = 0.f;
#pragma unroll 8
            for (int l = 0; l < LL; ++l)
                acc += attn_s[l] * z[(size_t)grp_s[l] * DX + tid];
            ctx[(size_t)m * DX + tid] = acc;
        }
        __syncthreads();
    }
}

// ---------------- logit = cat(h[idx,src], h[idx,dst], ctx) @ Wrel + brel ----
#define TML 4
__global__ __launch_bounds__(256) void k_logit(const float* __restrict__ h_grp,
                                               const int* __restrict__ idx,
                                               const int* __restrict__ srcv,
                                               const int* __restrict__ dstv,
                                               const float* __restrict__ ctx,
                                               const float* __restrict__ Wrel,
                                               const float* __restrict__ brel,
                                               float* __restrict__ out) {
    __shared__ __align__(16) float ins[TML][640];
    int m0 = blockIdx.x * TML;
    int tid = threadIdx.x;
    for (int mmj = 0; mmj < TML; ++mmj) {
        int m = m0 + mmj;
        int n = idx[m], s = srcv[m], d = dstv[m];
        ins[mmj][tid]       = h_grp[((size_t)n * LL + s) * DH + tid];
        ins[mmj][256 + tid] = h_grp[((size_t)n * LL + d) * DH + tid];
        if (tid < DX) ins[mmj][512 + tid] = ctx[(size_t)m * DX + tid];
    }
    __syncthreads();
    int mm = tid >> 6;
    int t = tid & 63;
    float acc = brel[t];
    const float4* in4 = (const float4*)ins[mm];
    for (int j4 = 0; j4 < 160; ++j4) {
        float4 iv = in4[j4];
        acc += iv.x * Wrel[(size_t)(j4 * 4 + 0) * 64 + t];
        acc += iv.y * Wrel[(size_t)(j4 * 4 + 1) * 64 + t];
        acc += iv.z * Wrel[(size_t)(j4 * 4 + 2) * 64 + t];
        acc += iv.w * Wrel[(size_t)(j4 * 4 + 3) * 64 + t];
    }
    out[(size_t)(m0 + mm) * 64 + t] = acc;
}

extern "C" void kernel_launch(void* const* d_in, const int* in_sizes, int n_in,
                              void* d_out, int out_size, void* d_ws, size_t ws_size,
                              hipStream_t stream) {
    const int*   mem     = (const int*)d_in[0];
    const int*   grp     = (const int*)d_in[1];
    const int*   pos2grp = (const int*)d_in[2];
    const float* h_grp   = (const float*)d_in[3];
    const int*   msk     = (const int*)d_in[4];
    const int*   idx     = (const int*)d_in[5];
    const int*   srcv    = (const int*)d_in[6];
    const int*   dstv    = (const int*)d_in[7];
    // d_in[8] = typ (unused by the reference)
    const float* tok_emb = (const float*)d_in[9];
    const float* Wq      = (const float*)d_in[10];
    const float* bq      = (const float*)d_in[11];
    const float* Wk      = (const float*)d_in[12];
    const float* bk      = (const float*)d_in[13];
    const float* Wrel    = (const float*)d_in[14];
    const float* brel    = (const float*)d_in[15];
    float* out = (float*)d_out;

    float* ws = (float*)d_ws;
    size_t off = 0;
    float* z    = ws + off; off += (size_t)GG * DX;       // 524288
    float* ctx  = ws + off; off += (size_t)MQ * DX;       // 1048576
    float* qk   = ws + off; off += (size_t)MQ * 256;      // 2097152
    float* qb   = ws + off; off += (size_t)MQ;            // 8192
    float* WkT  = ws + off; off += (size_t)DH * DH;       // 65536
    float* Wqk  = ws + off; off += (size_t)512 * 256;     // 131072
    float* wqb  = ws + off; off += 512;
    float* bqk  = ws + off; off += 256;
    float* sqb  = ws + off; off += 4;
    int* cnt        = (int*)(ws + off); off += GG;
    int* ofs        = (int*)(ws + off); off += GG;
    int* cur        = (int*)(ws + off); off += GG;
    int* tok_sorted = (int*)(ws + off); off += NMEM;
    int* ofs_n      = (int*)(ws + off); off += N_SEQ + 1;

    // segment-sum via counting sort (no float atomics)
    hipMemsetAsync(cnt, 0, GG * sizeof(int), stream);
    k_hist<<<NMEM / 256, 256, 0, stream>>>(grp, cnt);
    k_scan<<<1, 1024, 0, stream>>>(cnt, ofs, cur);
    k_permute<<<NMEM / 256, 256, 0, stream>>>(grp, mem, cur, tok_sorted);
    k_zsum<<<GG, 128, 0, stream>>>(ofs, cnt, tok_sorted, tok_emb, z);

    // per-n query ranges
    k_ranges<<<1, 1024, 0, stream>>>(idx, ofs_n);

    // folded weights
    dim3 tb(32, 32);
    dim3 tg(8, 8);
    k_transpose<<<tg, tb, 0, stream>>>(Wk, WkT);
    k_wqk<<<513, 256, 0, stream>>>(Wq, bq, bk, WkT, Wqk, wqb, bqk, sqb);

    // qk + qb directly from gathered qcat
    k_qk2<<<MQ / TMQ, 256, 0, stream>>>(h_grp, idx, srcv, dstv, Wqk, bqk, wqb, sqb, qk, qb);

    // per-n attention
    k_attn2<<<N_SEQ, 256, 0, stream>>>(h_grp, pos2grp, msk, z, qk, qb, ofs_n, ctx);

    k_logit<<<MQ / TML, 256, 0, stream>>>(h_grp, idx, srcv, dstv, ctx, Wrel, brel, out);
}

// Round 4
// 259.759 us; speedup vs baseline: 1.4869x; 1.4869x over previous
//
#include <hip/hip_runtime.h>
#include <math.h>

#define N_SEQ 1024
#define LL 64
#define DH 256
#define DX 128
#define MQ 8192
#define GG 4096
#define NTYP 64
#define NMEM 262144

__device__ __forceinline__ float bcast(float v, int l) {
    return __uint_as_float(__builtin_amdgcn_readlane(__float_as_uint(v), l));
}

// ---------------- counting-sort based segment sum ---------------------------
__global__ __launch_bounds__(256) void k_hist(const int* __restrict__ grp,
                                              int* __restrict__ cnt) {
    int i = blockIdx.x * 256 + threadIdx.x;
    if (i < NMEM) atomicAdd(&cnt[grp[i]], 1);
}

__global__ __launch_bounds__(1024) void k_scan(const int* __restrict__ cnt,
                                               int* __restrict__ ofs,
                                               int* __restrict__ cur) {
    __shared__ int wsum[16];
    int tid = threadIdx.x;
    int4 c = ((const int4*)cnt)[tid];
    int local = c.x + c.y + c.z + c.w;
    int lane = tid & 63, w = tid >> 6;
    int v = local;
    for (int off = 1; off < 64; off <<= 1) {
        int t = __shfl_up(v, off);
        if (lane >= off) v += t;
    }
    if (lane == 63) wsum[w] = v;
    __syncthreads();
    if (tid < 16) {
        int s = wsum[tid];
        for (int off = 1; off < 16; off <<= 1) {
            int t = __shfl_up(s, off);
            if (tid >= off) s += t;
        }
        wsum[tid] = s;
    }
    __syncthreads();
    int base = (w > 0 ? wsum[w - 1] : 0) + (v - local);
    int4 o;
    o.x = base;
    o.y = base + c.x;
    o.z = o.y + c.y;
    o.w = o.z + c.z;
    ((int4*)ofs)[tid] = o;
    ((int4*)cur)[tid] = o;
}

__global__ __launch_bounds__(256) void k_permute(const int* __restrict__ grp,
                                                 const int* __restrict__ mem,
                                                 int* __restrict__ cur,
                                                 int* __restrict__ tok_sorted) {
    int i = blockIdx.x * 256 + threadIdx.x;
    if (i < NMEM) {
        int g = grp[i];
        int pos = atomicAdd(&cur[g], 1);
        tok_sorted[pos] = mem[i];
    }
}

__global__ __launch_bounds__(128) void k_zsum(const int* __restrict__ ofs,
                                              const int* __restrict__ cnt,
                                              const int* __restrict__ tok_sorted,
                                              const float* __restrict__ tok_emb,
                                              float* __restrict__ z) {
    __shared__ int idxs[128];
    int g = blockIdx.x;
    int tid = threadIdx.x;
    int start = ofs[g], n = cnt[g];
    float acc = 0.f;
    for (int j0 = 0; j0 < n; j0 += 128) {
        __syncthreads();
        int rem = n - j0;
        if (tid < rem) idxs[tid] = tok_sorted[start + j0 + tid];
        __syncthreads();
        int kmax = rem < 128 ? rem : 128;
        for (int k = 0; k < kmax; ++k)
            acc += tok_emb[(size_t)idxs[k] * DX + tid];
    }
    z[(size_t)g * DX + tid] = acc;
}

// ---------------- zw[g][t] = sum_v z[g][v] * Wrel[512+v][t] -----------------
__global__ __launch_bounds__(64) void k_zw(const float* __restrict__ z,
                                           const float* __restrict__ Wrel,
                                           float* __restrict__ zw) {
    int g = blockIdx.x;
    int t = threadIdx.x;
    const float* zr = z + (size_t)g * DX;
    float acc = 0.f;
#pragma unroll 4
    for (int v = 0; v < DX; ++v)
        acc += zr[v] * Wrel[(size_t)(512 + v) * NTYP + t];
    zw[(size_t)g * NTYP + t] = acc;
}

// ---------------- transpose Wk ------------------------------------------------
__global__ void k_transpose(const float* __restrict__ Wk, float* __restrict__ WkT) {
    __shared__ float tile[32][33];
    int tx = threadIdx.x, ty = threadIdx.y;
    int bx = blockIdx.x, by = blockIdx.y;
    tile[ty][tx] = Wk[(size_t)(by * 32 + ty) * 256 + bx * 32 + tx];
    __syncthreads();
    WkT[(size_t)(bx * 32 + ty) * 256 + by * 32 + tx] = tile[tx][ty];
}

// ---------------- Wqk = Wq @ Wk^T etc. --------------------------------------
__global__ __launch_bounds__(256) void k_wqk(const float* __restrict__ Wq,
                                             const float* __restrict__ bq,
                                             const float* __restrict__ bk,
                                             const float* __restrict__ WkT,
                                             float* __restrict__ Wqk,
                                             float* __restrict__ wqb,
                                             float* __restrict__ bqk,
                                             float* __restrict__ sqb) {
    __shared__ float row[256];
    __shared__ float red[4];
    int j = blockIdx.x;
    int tid = threadIdx.x;
    if (j < 512) {
        row[tid] = Wq[(size_t)j * 256 + tid];
        __syncthreads();
        float acc = 0.f;
#pragma unroll 4
        for (int e = 0; e < 256; ++e) acc += row[e] * WkT[(size_t)e * 256 + tid];
        Wqk[(size_t)j * 256 + tid] = acc;
        float p = row[tid] * bk[tid];
        for (int o = 32; o; o >>= 1) p += __shfl_xor(p, o);
        if ((tid & 63) == 0) red[tid >> 6] = p;
        __syncthreads();
        if (tid == 0) wqb[j] = red[0] + red[1] + red[2] + red[3];
    } else {
        float acc = 0.f;
#pragma unroll 4
        for (int e = 0; e < 256; ++e) acc += bq[e] * WkT[(size_t)e * 256 + tid];
        bqk[tid] = acc;
        float p = bq[tid] * bk[tid];
        for (int o = 32; o; o >>= 1) p += __shfl_xor(p, o);
        if ((tid & 63) == 0) red[tid >> 6] = p;
        __syncthreads();
        if (tid == 0) sqb[0] = red[0] + red[1] + red[2] + red[3];
    }
}

// ---------------- qk[m] = qcat@Wqk + bqk ; qb[m] = qcat·wqb + sqb -----------
#define TMQ 16
__global__ __launch_bounds__(256) void k_qk2(const float* __restrict__ h_grp,
                                             const int* __restrict__ idx,
                                             const int* __restrict__ srcv,
                                             const int* __restrict__ dstv,
                                             const float* __restrict__ Wqk,
                                             const float* __restrict__ bqk,
                                             const float* __restrict__ wqb,
                                             const float* __restrict__ sqb,
                                             float* __restrict__ qk,
                                             float* __restrict__ qb) {
    __shared__ __align__(16) float qs[TMQ][512];
    __shared__ float part[TMQ][16];
    int bid = blockIdx.x;
    int swz = (bid & 7) * 64 + (bid >> 3);     // 512 blocks, XCD-chunked
    int m0 = swz * TMQ;
    int tid = threadIdx.x;
    for (int mm = 0; mm < TMQ; ++mm) {
        int m = m0 + mm;
        int n = idx[m], s = srcv[m], d = dstv[m];
        qs[mm][tid]       = h_grp[((size_t)n * LL + s) * DH + tid];
        qs[mm][256 + tid] = h_grp[((size_t)n * LL + d) * DH + tid];
    }
    __syncthreads();
    float acc[TMQ];
    float b = bqk[tid];
#pragma unroll
    for (int mm = 0; mm < TMQ; ++mm) acc[mm] = b;
    for (int j4 = 0; j4 < 128; ++j4) {
        float w0 = Wqk[(size_t)(j4 * 4 + 0) * 256 + tid];
        float w1 = Wqk[(size_t)(j4 * 4 + 1) * 256 + tid];
        float w2 = Wqk[(size_t)(j4 * 4 + 2) * 256 + tid];
        float w3 = Wqk[(size_t)(j4 * 4 + 3) * 256 + tid];
#pragma unroll
        for (int mm = 0; mm < TMQ; ++mm) {
            float4 qv = ((const float4*)qs[mm])[j4];
            acc[mm] += qv.x * w0 + qv.y * w1 + qv.z * w2 + qv.w * w3;
        }
    }
    for (int mm = 0; mm < TMQ; ++mm)
        qk[(size_t)(m0 + mm) * 256 + tid] = acc[mm];
    {
        int mm = tid >> 4, seg = tid & 15;
        float p = 0.f;
        for (int j = seg * 32; j < seg * 32 + 32; ++j)
            p += qs[mm][j] * wqb[j];
        part[mm][seg] = p;
    }
    __syncthreads();
    if (tid < TMQ) {
        float s = sqb[0];
        for (int k = 0; k < 16; ++k) s += part[tid][k];
        qb[m0 + tid] = s;
    }
}

// ---------------- attention: one wave per query, no LDS, no syncs -----------
__global__ __launch_bounds__(256) void k_attn3(const float* __restrict__ h_grp,
                                               const int* __restrict__ idx,
                                               const int* __restrict__ pos2grp,
                                               const int* __restrict__ msk,
                                               const float* __restrict__ zw,
                                               const float* __restrict__ qk,
                                               const float* __restrict__ qb,
                                               float* __restrict__ ctxw) {
    int bid = blockIdx.x;
    int swz = (bid & 7) * 256 + (bid >> 3);    // 2048 blocks, XCD-chunked
    int w = threadIdx.x >> 6;
    int lane = threadIdx.x & 63;
    int m = swz * 4 + w;
    int n = idx[m];

    // lane holds qk[4*lane .. 4*lane+3]
    float4 qv = ((const float4*)(qk + (size_t)m * 256))[lane];
    float qbv = qb[m];

    // scores: lane l computes row l's 256-dot via readlane broadcast of qk
    const float4* hrow = (const float4*)(h_grp + ((size_t)n * LL + lane) * DH);
    float a0 = 0.f, a1 = 0.f, a2 = 0.f, a3 = 0.f;
#pragma unroll 8
    for (int e4 = 0; e4 < 64; ++e4) {
        float4 hv = hrow[e4];
        a0 += hv.x * bcast(qv.x, e4);
        a1 += hv.y * bcast(qv.y, e4);
        a2 += hv.z * bcast(qv.z, e4);
        a3 += hv.w * bcast(qv.w, e4);
    }
    int mk = msk[n * LL + lane];
    int g  = pos2grp[n * LL + lane];
    float s = ((a0 + a1) + (a2 + a3) + qbv) * (1.0f / 16.0f);
    float sv = mk ? s : -INFINITY;
    // softmax across 64 lanes
    float mx = sv;
    for (int o = 32; o; o >>= 1) mx = fmaxf(mx, __shfl_xor(mx, o));
    float p = mk ? __expf(sv - mx) : 0.f;
    float sum = p;
    for (int o = 32; o; o >>= 1) sum += __shfl_xor(sum, o);
    float attn = p / sum;

    // ctxw[m][t] = sum_l attn_l * zw[g_l][t]   (t = lane)
    float acc = 0.f;
    for (int l = 0; l < 64; ++l) {
        float al = bcast(attn, l);
        if (al != 0.f) {
            int gl = __builtin_amdgcn_readlane(g, l);
            acc += al * zw[(size_t)gl * NTYP + lane];
        }
    }
    ctxw[(size_t)m * NTYP + lane] = acc;
}

// ---------------- out[m] = brel + ctxw[m] + qcat @ Wrel[0:512] --------------
#define TML 4
__global__ __launch_bounds__(256) void k_logit2(const float* __restrict__ h_grp,
                                                const int* __restrict__ idx,
                                                const int* __restrict__ srcv,
                                                const int* __restrict__ dstv,
                                                const float* __restrict__ ctxw,
                                                const float* __restrict__ Wrel,
                                                const float* __restrict__ brel,
                                                float* __restrict__ out) {
    __shared__ __align__(16) float ins[TML][512];
    int bid = blockIdx.x;
    int swz = (bid & 7) * 256 + (bid >> 3);    // 2048 blocks
    int m0 = swz * TML;
    int tid = threadIdx.x;
    for (int mmj = 0; mmj < TML; ++mmj) {
        int m = m0 + mmj;
        int n = idx[m], s = srcv[m], d = dstv[m];
        ins[mmj][tid]       = h_grp[((size_t)n * LL + s) * DH + tid];
        ins[mmj][256 + tid] = h_grp[((size_t)n * LL + d) * DH + tid];
    }
    __syncthreads();
    int mm = tid >> 6;
    int t = tid & 63;
    int m = m0 + mm;
    float acc = brel[t] + ctxw[(size_t)m * NTYP + t];
    const float4* in4 = (const float4*)ins[mm];
    for (int j4 = 0; j4 < 128; ++j4) {
        float4 iv = in4[j4];
        acc += iv.x * Wrel[(size_t)(j4 * 4 + 0) * NTYP + t];
        acc += iv.y * Wrel[(size_t)(j4 * 4 + 1) * NTYP + t];
        acc += iv.z * Wrel[(size_t)(j4 * 4 + 2) * NTYP + t];
        acc += iv.w * Wrel[(size_t)(j4 * 4 + 3) * NTYP + t];
    }
    out[(size_t)m * NTYP + t] = acc;
}

extern "C" void kernel_launch(void* const* d_in, const int* in_sizes, int n_in,
                              void* d_out, int out_size, void* d_ws, size_t ws_size,
                              hipStream_t stream) {
    const int*   mem     = (const int*)d_in[0];
    const int*   grp     = (const int*)d_in[1];
    const int*   pos2grp = (const int*)d_in[2];
    const float* h_grp   = (const float*)d_in[3];
    const int*   msk     = (const int*)d_in[4];
    const int*   idx     = (const int*)d_in[5];
    const int*   srcv    = (const int*)d_in[6];
    const int*   dstv    = (const int*)d_in[7];
    // d_in[8] = typ (unused by the reference)
    const float* tok_emb = (const float*)d_in[9];
    const float* Wq      = (const float*)d_in[10];
    const float* bq      = (const float*)d_in[11];
    const float* Wk      = (const float*)d_in[12];
    const float* bk      = (const float*)d_in[13];
    const float* Wrel    = (const float*)d_in[14];
    const float* brel    = (const float*)d_in[15];
    float* out = (float*)d_out;

    float* ws = (float*)d_ws;
    size_t off = 0;
    float* z    = ws + off; off += (size_t)GG * DX;       // 524288
    float* zw   = ws + off; off += (size_t)GG * NTYP;     // 262144
    float* qk   = ws + off; off += (size_t)MQ * 256;      // 2097152
    float* qb   = ws + off; off += (size_t)MQ;            // 8192
    float* ctxw = ws + off; off += (size_t)MQ * NTYP;     // 524288
    float* WkT  = ws + off; off += (size_t)DH * DH;       // 65536
    float* Wqk  = ws + off; off += (size_t)512 * 256;     // 131072
    float* wqb  = ws + off; off += 512;
    float* bqk  = ws + off; off += 256;
    float* sqb  = ws + off; off += 4;
    int* cnt        = (int*)(ws + off); off += GG;
    int* ofs        = (int*)(ws + off); off += GG;
    int* cur        = (int*)(ws + off); off += GG;
    int* tok_sorted = (int*)(ws + off); off += NMEM;

    // segment-sum via counting sort (no float atomics)
    hipMemsetAsync(cnt, 0, GG * sizeof(int), stream);
    k_hist<<<NMEM / 256, 256, 0, stream>>>(grp, cnt);
    k_scan<<<1, 1024, 0, stream>>>(cnt, ofs, cur);
    k_permute<<<NMEM / 256, 256, 0, stream>>>(grp, mem, cur, tok_sorted);
    k_zsum<<<GG, 128, 0, stream>>>(ofs, cnt, tok_sorted, tok_emb, z);
    k_zw<<<GG, 64, 0, stream>>>(z, Wrel, zw);

    // folded weights
    dim3 tb(32, 32);
    dim3 tg(8, 8);
    k_transpose<<<tg, tb, 0, stream>>>(Wk, WkT);
    k_wqk<<<513, 256, 0, stream>>>(Wq, bq, bk, WkT, Wqk, wqb, bqk, sqb);

    // qk + qb directly from gathered qcat
    k_qk2<<<MQ / TMQ, 256, 0, stream>>>(h_grp, idx, srcv, dstv, Wqk, bqk, wqb, sqb, qk, qb);

    // one wave per query
    k_attn3<<<2048, 256, 0, stream>>>(h_grp, idx, pos2grp, msk, zw, qk, qb, ctxw);

    k_logit2<<<2048, 256, 0, stream>>>(h_grp, idx, srcv, dstv, ctxw, Wrel, brel, out);
}

// Round 5
// 206.658 us; speedup vs baseline: 1.8689x; 1.2569x over previous
//
#include <hip/hip_runtime.h>
#include <math.h>

#define N_SEQ 1024
#define LL 64
#define DH 256
#define DX 128
#define MQ 8192
#define GG 4096
#define NTYP 64
#define NMEM 262144

__device__ __forceinline__ float bcast(float v, int l) {
    return __uint_as_float(__builtin_amdgcn_readlane(__float_as_uint(v), l));
}

// ---------------- counting-sort based segment sum ---------------------------
__global__ __launch_bounds__(256) void k_hist(const int* __restrict__ grp,
                                              int* __restrict__ cnt) {
    int i = blockIdx.x * 256 + threadIdx.x;
    if (i < NMEM) atomicAdd(&cnt[grp[i]], 1);
}

__global__ __launch_bounds__(1024) void k_scan(const int* __restrict__ cnt,
                                               int* __restrict__ ofs,
                                               int* __restrict__ cur) {
    __shared__ int wsum[16];
    int tid = threadIdx.x;
    int4 c = ((const int4*)cnt)[tid];
    int local = c.x + c.y + c.z + c.w;
    int lane = tid & 63, w = tid >> 6;
    int v = local;
    for (int off = 1; off < 64; off <<= 1) {
        int t = __shfl_up(v, off);
        if (lane >= off) v += t;
    }
    if (lane == 63) wsum[w] = v;
    __syncthreads();
    if (tid < 16) {
        int s = wsum[tid];
        for (int off = 1; off < 16; off <<= 1) {
            int t = __shfl_up(s, off);
            if (tid >= off) s += t;
        }
        wsum[tid] = s;
    }
    __syncthreads();
    int base = (w > 0 ? wsum[w - 1] : 0) + (v - local);
    int4 o;
    o.x = base;
    o.y = base + c.x;
    o.z = o.y + c.y;
    o.w = o.z + c.z;
    ((int4*)ofs)[tid] = o;
    ((int4*)cur)[tid] = o;
}

__global__ __launch_bounds__(256) void k_permute(const int* __restrict__ grp,
                                                 const int* __restrict__ mem,
                                                 int* __restrict__ cur,
                                                 int* __restrict__ tok_sorted) {
    int i = blockIdx.x * 256 + threadIdx.x;
    if (i < NMEM) {
        int g = grp[i];
        int pos = atomicAdd(&cur[g], 1);
        tok_sorted[pos] = mem[i];
    }
}

// z[g] = sum tok_emb rows; fused: zw[g] = z[g] @ Wrel[512:640]
__global__ __launch_bounds__(128) void k_zsum(const int* __restrict__ ofs,
                                              const int* __restrict__ cnt,
                                              const int* __restrict__ tok_sorted,
                                              const float* __restrict__ tok_emb,
                                              const float* __restrict__ Wrel,
                                              float* __restrict__ zw) {
    __shared__ int idxs[128];
    __shared__ float zs[128];
    int g = blockIdx.x;
    int tid = threadIdx.x;
    int start = ofs[g], n = cnt[g];
    float acc = 0.f;
    for (int j0 = 0; j0 < n; j0 += 128) {
        __syncthreads();
        int rem = n - j0;
        if (tid < rem) idxs[tid] = tok_sorted[start + j0 + tid];
        __syncthreads();
        int kmax = rem < 128 ? rem : 128;
        for (int k = 0; k < kmax; ++k)
            acc += tok_emb[(size_t)idxs[k] * DX + tid];
    }
    zs[tid] = acc;
    __syncthreads();
    if (tid < NTYP) {
        float a2 = 0.f;
#pragma unroll 8
        for (int v = 0; v < DX; ++v)
            a2 += zs[v] * Wrel[(size_t)(512 + v) * NTYP + tid];
        zw[(size_t)g * NTYP + tid] = a2;
    }
}

// ---------------- transpose Wk ------------------------------------------------
__global__ void k_transpose(const float* __restrict__ Wk, float* __restrict__ WkT) {
    __shared__ float tile[32][33];
    int tx = threadIdx.x, ty = threadIdx.y;
    int bx = blockIdx.x, by = blockIdx.y;
    tile[ty][tx] = Wk[(size_t)(by * 32 + ty) * 256 + bx * 32 + tx];
    __syncthreads();
    WkT[(size_t)(bx * 32 + ty) * 256 + by * 32 + tx] = tile[tx][ty];
}

// ---------------- Wqk = Wq @ Wk^T etc. --------------------------------------
__global__ __launch_bounds__(256) void k_wqk(const float* __restrict__ Wq,
                                             const float* __restrict__ bq,
                                             const float* __restrict__ bk,
                                             const float* __restrict__ WkT,
                                             float* __restrict__ Wqk,
                                             float* __restrict__ wqb,
                                             float* __restrict__ bqk,
                                             float* __restrict__ sqb) {
    __shared__ float row[256];
    __shared__ float red[4];
    int j = blockIdx.x;
    int tid = threadIdx.x;
    if (j < 512) {
        row[tid] = Wq[(size_t)j * 256 + tid];
        __syncthreads();
        float acc = 0.f;
#pragma unroll 4
        for (int e = 0; e < 256; ++e) acc += row[e] * WkT[(size_t)e * 256 + tid];
        Wqk[(size_t)j * 256 + tid] = acc;
        float p = row[tid] * bk[tid];
        for (int o = 32; o; o >>= 1) p += __shfl_xor(p, o);
        if ((tid & 63) == 0) red[tid >> 6] = p;
        __syncthreads();
        if (tid == 0) wqb[j] = red[0] + red[1] + red[2] + red[3];
    } else {
        float acc = 0.f;
#pragma unroll 4
        for (int e = 0; e < 256; ++e) acc += bq[e] * WkT[(size_t)e * 256 + tid];
        bqk[tid] = acc;
        float p = bq[tid] * bk[tid];
        for (int o = 32; o; o >>= 1) p += __shfl_xor(p, o);
        if ((tid & 63) == 0) red[tid >> 6] = p;
        __syncthreads();
        if (tid == 0) sqb[0] = red[0] + red[1] + red[2] + red[3];
    }
}

// ---------------- qk[m] = qcat@Wqk + bqk ; qb[m] = qcat·wqb + sqb -----------
#define TMQ 16
__global__ __launch_bounds__(256) void k_qk2(const float* __restrict__ h_grp,
                                             const int* __restrict__ idx,
                                             const int* __restrict__ srcv,
                                             const int* __restrict__ dstv,
                                             const float* __restrict__ Wqk,
                                             const float* __restrict__ bqk,
                                             const float* __restrict__ wqb,
                                             const float* __restrict__ sqb,
                                             float* __restrict__ qk,
                                             float* __restrict__ qb) {
    __shared__ __align__(16) float qs[TMQ][512];
    __shared__ float part[TMQ][16];
    int bid = blockIdx.x;
    int swz = (bid & 7) * 64 + (bid >> 3);     // 512 blocks, XCD-chunked
    int m0 = swz * TMQ;
    int tid = threadIdx.x;
    for (int mm = 0; mm < TMQ; ++mm) {
        int m = m0 + mm;
        int n = idx[m], s = srcv[m], d = dstv[m];
        qs[mm][tid]       = h_grp[((size_t)n * LL + s) * DH + tid];
        qs[mm][256 + tid] = h_grp[((size_t)n * LL + d) * DH + tid];
    }
    __syncthreads();
    float acc[TMQ];
    float b = bqk[tid];
#pragma unroll
    for (int mm = 0; mm < TMQ; ++mm) acc[mm] = b;
    for (int j4 = 0; j4 < 128; ++j4) {
        float w0 = Wqk[(size_t)(j4 * 4 + 0) * 256 + tid];
        float w1 = Wqk[(size_t)(j4 * 4 + 1) * 256 + tid];
        float w2 = Wqk[(size_t)(j4 * 4 + 2) * 256 + tid];
        float w3 = Wqk[(size_t)(j4 * 4 + 3) * 256 + tid];
#pragma unroll
        for (int mm = 0; mm < TMQ; ++mm) {
            float4 qv = ((const float4*)qs[mm])[j4];
            acc[mm] += qv.x * w0 + qv.y * w1 + qv.z * w2 + qv.w * w3;
        }
    }
    for (int mm = 0; mm < TMQ; ++mm)
        qk[(size_t)(m0 + mm) * 256 + tid] = acc[mm];
    {
        int mm = tid >> 4, seg = tid & 15;
        float p = 0.f;
        for (int j = seg * 32; j < seg * 32 + 32; ++j)
            p += qs[mm][j] * wqb[j];
        part[mm][seg] = p;
    }
    __syncthreads();
    if (tid < TMQ) {
        float s = sqb[0];
        for (int k = 0; k < 16; ++k) s += part[tid][k];
        qb[m0 + tid] = s;
    }
}

// ---------------- attention: one wave/query, coalesced streaming scores -----
__global__ __launch_bounds__(256) void k_attn4(const float* __restrict__ h_grp,
                                               const int* __restrict__ idx,
                                               const int* __restrict__ pos2grp,
                                               const int* __restrict__ msk,
                                               const float* __restrict__ zw,
                                               const float* __restrict__ qk,
                                               const float* __restrict__ qb,
                                               float* __restrict__ ctxw) {
    int bid = blockIdx.x;
    int swz = (bid & 7) * 256 + (bid >> 3);    // 2048 blocks, XCD-chunked
    int w = threadIdx.x >> 6;
    int lane = threadIdx.x & 63;
    int m = swz * 4 + w;
    int n = idx[m];
    int j = lane & 15;        // column-chunk within 16-lane group
    int gr = lane >> 4;       // group 0..3 owns rows 16*gr..16*gr+15

    const float4* qk4 = (const float4*)(qk + (size_t)m * 256);
    float4 qv0 = qk4[j];
    float4 qv1 = qk4[j + 16];
    float4 qv2 = qk4[j + 32];
    float4 qv3 = qk4[j + 48];

    const float* hbase = h_grp + (size_t)n * LL * DH + (size_t)gr * 16 * DH;
    float score = 0.f;
#pragma unroll
    for (int r = 0; r < 16; ++r) {
        const float4* hr = (const float4*)(hbase + r * DH);
        float4 h0 = hr[j];
        float4 h1 = hr[j + 16];
        float4 h2 = hr[j + 32];
        float4 h3 = hr[j + 48];
        float p = h0.x * qv0.x + h0.y * qv0.y + h0.z * qv0.z + h0.w * qv0.w
                + h1.x * qv1.x + h1.y * qv1.y + h1.z * qv1.z + h1.w * qv1.w
                + h2.x * qv2.x + h2.y * qv2.y + h2.z * qv2.z + h2.w * qv2.w
                + h3.x * qv3.x + h3.y * qv3.y + h3.z * qv3.z + h3.w * qv3.w;
        p += __shfl_xor(p, 1);
        p += __shfl_xor(p, 2);
        p += __shfl_xor(p, 4);
        p += __shfl_xor(p, 8);
        if (j == r) score = p;   // lane l ends with score of row l
    }

    float qbv = qb[m];
    int mk = msk[n * LL + lane];
    int g  = pos2grp[n * LL + lane];
    float sv = mk ? (score + qbv) * (1.0f / 16.0f) : -INFINITY;
    float mx = sv;
    for (int o = 32; o; o >>= 1) mx = fmaxf(mx, __shfl_xor(mx, o));
    float p = mk ? __expf(sv - mx) : 0.f;
    float sum = p;
    for (int o = 32; o; o >>= 1) sum += __shfl_xor(sum, o);
    float attn = p / sum;

    // ctxw[m][lane] = sum_l attn_l * zw[g_l][lane]  (branch-free, unrolled)
    float acc = 0.f;
#pragma unroll 16
    for (int l = 0; l < 64; ++l) {
        float al = bcast(attn, l);
        int gl = __builtin_amdgcn_readlane(g, l);
        acc += al * zw[(size_t)gl * NTYP + lane];
    }
    ctxw[(size_t)m * NTYP + lane] = acc;
}

// ---------------- out[m] = brel + ctxw[m] + qcat @ Wrel[0:512] --------------
#define TML 4
__global__ __launch_bounds__(256) void k_logit2(const float* __restrict__ h_grp,
                                                const int* __restrict__ idx,
                                                const int* __restrict__ srcv,
                                                const int* __restrict__ dstv,
                                                const float* __restrict__ ctxw,
                                                const float* __restrict__ Wrel,
                                                const float* __restrict__ brel,
                                                float* __restrict__ out) {
    __shared__ __align__(16) float ins[TML][512];
    int bid = blockIdx.x;
    int swz = (bid & 7) * 256 + (bid >> 3);    // 2048 blocks
    int m0 = swz * TML;
    int tid = threadIdx.x;
    for (int mmj = 0; mmj < TML; ++mmj) {
        int m = m0 + mmj;
        int n = idx[m], s = srcv[m], d = dstv[m];
        ins[mmj][tid]       = h_grp[((size_t)n * LL + s) * DH + tid];
        ins[mmj][256 + tid] = h_grp[((size_t)n * LL + d) * DH + tid];
    }
    __syncthreads();
    int mm = tid >> 6;
    int t = tid & 63;
    int m = m0 + mm;
    float acc = brel[t] + ctxw[(size_t)m * NTYP + t];
    const float4* in4 = (const float4*)ins[mm];
    for (int j4 = 0; j4 < 128; ++j4) {
        float4 iv = in4[j4];
        acc += iv.x * Wrel[(size_t)(j4 * 4 + 0) * NTYP + t];
        acc += iv.y * Wrel[(size_t)(j4 * 4 + 1) * NTYP + t];
        acc += iv.z * Wrel[(size_t)(j4 * 4 + 2) * NTYP + t];
        acc += iv.w * Wrel[(size_t)(j4 * 4 + 3) * NTYP + t];
    }
    out[(size_t)m * NTYP + t] = acc;
}

extern "C" void kernel_launch(void* const* d_in, const int* in_sizes, int n_in,
                              void* d_out, int out_size, void* d_ws, size_t ws_size,
                              hipStream_t stream) {
    const int*   mem     = (const int*)d_in[0];
    const int*   grp     = (const int*)d_in[1];
    const int*   pos2grp = (const int*)d_in[2];
    const float* h_grp   = (const float*)d_in[3];
    const int*   msk     = (const int*)d_in[4];
    const int*   idx     = (const int*)d_in[5];
    const int*   srcv    = (const int*)d_in[6];
    const int*   dstv    = (const int*)d_in[7];
    // d_in[8] = typ (unused by the reference)
    const float* tok_emb = (const float*)d_in[9];
    const float* Wq      = (const float*)d_in[10];
    const float* bq      = (const float*)d_in[11];
    const float* Wk      = (const float*)d_in[12];
    const float* bk      = (const float*)d_in[13];
    const float* Wrel    = (const float*)d_in[14];
    const float* brel    = (const float*)d_in[15];
    float* out = (float*)d_out;

    float* ws = (float*)d_ws;
    size_t off = 0;
    float* zw   = ws + off; off += (size_t)GG * NTYP;     // 262144
    float* qk   = ws + off; off += (size_t)MQ * 256;      // 2097152
    float* qb   = ws + off; off += (size_t)MQ;            // 8192
    float* ctxw = ws + off; off += (size_t)MQ * NTYP;     // 524288
    float* WkT  = ws + off; off += (size_t)DH * DH;       // 65536
    float* Wqk  = ws + off; off += (size_t)512 * 256;     // 131072
    float* wqb  = ws + off; off += 512;
    float* bqk  = ws + off; off += 256;
    float* sqb  = ws + off; off += 4;
    int* cnt        = (int*)(ws + off); off += GG;
    int* ofs        = (int*)(ws + off); off += GG;
    int* cur        = (int*)(ws + off); off += GG;
    int* tok_sorted = (int*)(ws + off); off += NMEM;

    // segment-sum via counting sort (no float atomics), fused zw projection
    hipMemsetAsync(cnt, 0, GG * sizeof(int), stream);
    k_hist<<<NMEM / 256, 256, 0, stream>>>(grp, cnt);
    k_scan<<<1, 1024, 0, stream>>>(cnt, ofs, cur);
    k_permute<<<NMEM / 256, 256, 0, stream>>>(grp, mem, cur, tok_sorted);
    k_zsum<<<GG, 128, 0, stream>>>(ofs, cnt, tok_sorted, tok_emb, Wrel, zw);

    // folded weights
    dim3 tb(32, 32);
    dim3 tg(8, 8);
    k_transpose<<<tg, tb, 0, stream>>>(Wk, WkT);
    k_wqk<<<513, 256, 0, stream>>>(Wq, bq, bk, WkT, Wqk, wqb, bqk, sqb);

    // qk + qb directly from gathered qcat
    k_qk2<<<MQ / TMQ, 256, 0, stream>>>(h_grp, idx, srcv, dstv, Wqk, bqk, wqb, sqb, qk, qb);

    // one wave per query, coalesced score streaming
    k_attn4<<<2048, 256, 0, stream>>>(h_grp, idx, pos2grp, msk, zw, qk, qb, ctxw);

    k_logit2<<<2048, 256, 0, stream>>>(h_grp, idx, srcv, dstv, ctxw, Wrel, brel, out);
}

// Round 6
// 141.831 us; speedup vs baseline: 2.7231x; 1.4571x over previous
//
#include <hip/hip_runtime.h>
#include <math.h>

#define N_SEQ 1024
#define LL 64
#define DH 256
#define DX 128
#define MQ 8192
#define GG 4096
#define NTYP 64
#define NMEM 262144

typedef __attribute__((ext_vector_type(8))) short short8v;
typedef __attribute__((ext_vector_type(4))) float float4v;

__device__ __forceinline__ float bcast(float v, int l) {
    return __uint_as_float(__builtin_amdgcn_readlane(__float_as_uint(v), l));
}

__device__ __forceinline__ unsigned short f2bf(float x) {
    unsigned int u = __float_as_uint(x);
    u += 0x7FFFu + ((u >> 16) & 1u);   // round-to-nearest-even
    return (unsigned short)(u >> 16);
}

// ---------------- counting-sort based segment sum ---------------------------
__global__ __launch_bounds__(256) void k_hist(const int* __restrict__ grp,
                                              int* __restrict__ cnt) {
    int i = blockIdx.x * 256 + threadIdx.x;
    if (i < NMEM) atomicAdd(&cnt[grp[i]], 1);
}

__global__ __launch_bounds__(1024) void k_scan(const int* __restrict__ cnt,
                                               int* __restrict__ ofs,
                                               int* __restrict__ cur) {
    __shared__ int wsum[16];
    int tid = threadIdx.x;
    int4 c = ((const int4*)cnt)[tid];
    int local = c.x + c.y + c.z + c.w;
    int lane = tid & 63, w = tid >> 6;
    int v = local;
    for (int off = 1; off < 64; off <<= 1) {
        int t = __shfl_up(v, off);
        if (lane >= off) v += t;
    }
    if (lane == 63) wsum[w] = v;
    __syncthreads();
    if (tid < 16) {
        int s = wsum[tid];
        for (int off = 1; off < 16; off <<= 1) {
            int t = __shfl_up(s, off);
            if (tid >= off) s += t;
        }
        wsum[tid] = s;
    }
    __syncthreads();
    int base = (w > 0 ? wsum[w - 1] : 0) + (v - local);
    int4 o;
    o.x = base;
    o.y = base + c.x;
    o.z = o.y + c.y;
    o.w = o.z + c.z;
    ((int4*)ofs)[tid] = o;
    ((int4*)cur)[tid] = o;
}

__global__ __launch_bounds__(256) void k_permute(const int* __restrict__ grp,
                                                 const int* __restrict__ mem,
                                                 int* __restrict__ cur,
                                                 int* __restrict__ tok_sorted) {
    int i = blockIdx.x * 256 + threadIdx.x;
    if (i < NMEM) {
        int g = grp[i];
        int pos = atomicAdd(&cur[g], 1);
        tok_sorted[pos] = mem[i];
    }
}

// z[g] = sum tok_emb rows; fused: zw[g] = z[g] @ Wrel[512:640]
__global__ __launch_bounds__(128) void k_zsum(const int* __restrict__ ofs,
                                              const int* __restrict__ cnt,
                                              const int* __restrict__ tok_sorted,
                                              const float* __restrict__ tok_emb,
                                              const float* __restrict__ Wrel,
                                              float* __restrict__ zw) {
    __shared__ int idxs[128];
    __shared__ float zs[128];
    int g = blockIdx.x;
    int tid = threadIdx.x;
    int start = ofs[g], n = cnt[g];
    float acc = 0.f;
    for (int j0 = 0; j0 < n; j0 += 128) {
        __syncthreads();
        int rem = n - j0;
        if (tid < rem) idxs[tid] = tok_sorted[start + j0 + tid];
        __syncthreads();
        int kmax = rem < 128 ? rem : 128;
        for (int k = 0; k < kmax; ++k)
            acc += tok_emb[(size_t)idxs[k] * DX + tid];
    }
    zs[tid] = acc;
    __syncthreads();
    if (tid < NTYP) {
        float a2 = 0.f;
#pragma unroll 8
        for (int v = 0; v < DX; ++v)
            a2 += zs[v] * Wrel[(size_t)(512 + v) * NTYP + tid];
        zw[(size_t)g * NTYP + tid] = a2;
    }
}

// ---------------- build BT[320][512] bf16 and bias[320] ---------------------
// rows 0..255:  BT[n][j] = bf16( sum_e Wq[j,e] * Wk[n,e] ),  bias[n] = Wk[n,:]·bq
// rows 256..319: BT[n][j] = bf16( Wrel[j, n-256] ),           bias[n] = 0
__global__ __launch_bounds__(256) void k_wqkb(const float* __restrict__ Wq,
                                              const float* __restrict__ bq,
                                              const float* __restrict__ Wk,
                                              const float* __restrict__ Wrel,
                                              unsigned short* __restrict__ BT,
                                              float* __restrict__ bias) {
    int n = blockIdx.x;
    int tid = threadIdx.x;
    if (n < 256) {
        __shared__ float wk_s[256];
        __shared__ float red[4];
        wk_s[tid] = Wk[(size_t)n * 256 + tid];
        __syncthreads();
#pragma unroll
        for (int jj = 0; jj < 2; ++jj) {
            int j = tid + jj * 256;
            const float* wq = Wq + (size_t)j * 256;
            float acc = 0.f;
#pragma unroll 4
            for (int e = 0; e < 256; ++e) acc += wq[e] * wk_s[e];
            BT[(size_t)n * 512 + j] = f2bf(acc);
        }
        float p = wk_s[tid] * bq[tid];
        for (int o = 32; o; o >>= 1) p += __shfl_xor(p, o);
        if ((tid & 63) == 0) red[tid >> 6] = p;
        __syncthreads();
        if (tid == 0) bias[n] = red[0] + red[1] + red[2] + red[3];
    } else {
        int t = n - 256;
#pragma unroll
        for (int jj = 0; jj < 2; ++jj) {
            int j = tid + jj * 256;
            BT[(size_t)n * 512 + j] = f2bf(Wrel[(size_t)j * NTYP + t]);
        }
        if (tid == 0) bias[n] = 0.f;
    }
}

// ---------------- MFMA GEMM: C[8192][320] = A_gathered[8192][512] @ B -------
// cols 0..255 -> qk ; cols 256..319 -> part (logit partial)
__global__ __launch_bounds__(256) void k_gemm(const float* __restrict__ h_grp,
                                              const int* __restrict__ idx,
                                              const int* __restrict__ srcv,
                                              const int* __restrict__ dstv,
                                              const unsigned short* __restrict__ BT,
                                              const float* __restrict__ bias,
                                              float* __restrict__ qk,
                                              float* __restrict__ part) {
    __shared__ __align__(16) unsigned short A[16 * 512];
    __shared__ int ns[16], ss[16], dsv[16];
    int bid = blockIdx.x;
    int swz = (bid & 7) * 64 + (bid >> 3);   // 512 blocks, XCD-chunked
    int m0 = swz * 16;
    int tid = threadIdx.x;
    if (tid < 16) {
        int m = m0 + tid;
        ns[tid] = idx[m];
        ss[tid] = srcv[m];
        dsv[tid] = dstv[m];
    }
    __syncthreads();
    // stage A: thread t -> row r = t>>4, k-cols kc..kc+31
    {
        int r = tid >> 4;
        int kc = (tid & 15) * 32;
        const float* src = h_grp +
            ((size_t)ns[r] * LL + (kc < 256 ? ss[r] : dsv[r])) * DH + (kc & 255);
        const float4* s4 = (const float4*)src;
        float4 f[8];
#pragma unroll
        for (int j = 0; j < 8; ++j) f[j] = s4[j];
        unsigned short* Arow = A + r * 512;
#pragma unroll
        for (int j = 0; j < 4; ++j) {
            int c = (kc >> 3) + j;
            int cs = (c & ~7) | ((c & 7) ^ (r & 7));
            unsigned short tmp[8];
            float4 lo = f[j * 2], hi = f[j * 2 + 1];
            tmp[0] = f2bf(lo.x); tmp[1] = f2bf(lo.y);
            tmp[2] = f2bf(lo.z); tmp[3] = f2bf(lo.w);
            tmp[4] = f2bf(hi.x); tmp[5] = f2bf(hi.y);
            tmp[6] = f2bf(hi.z); tmp[7] = f2bf(hi.w);
            *(int4*)(Arow + cs * 8) = *(int4*)tmp;
        }
    }
    __syncthreads();

    int w = tid >> 6, lane = tid & 63;
    int r = lane & 15;          // A row / C col
    int q = lane >> 4;          // k-octet / C row-quad
    int n0 = w * 80;
    float4v acc[5];
#pragma unroll
    for (int t = 0; t < 5; ++t) {
        float b = bias[n0 + t * 16 + r];
        acc[t] = (float4v){b, b, b, b};
    }
    const unsigned short* Arow = A + r * 512;
#pragma unroll 2
    for (int ks = 0; ks < 16; ++ks) {
        int c = ks * 4 + q;
        int cs = (c & ~7) | ((c & 7) ^ (r & 7));
        short8v a = *(const short8v*)(Arow + cs * 8);
        int kk = ks * 32 + q * 8;
#pragma unroll
        for (int t = 0; t < 5; ++t) {
            int n = n0 + t * 16 + r;
            short8v b = *(const short8v*)(BT + (size_t)n * 512 + kk);
            acc[t] = __builtin_amdgcn_mfma_f32_16x16x32_bf16(a, b, acc[t], 0, 0, 0);
        }
    }
    // write: C row = m0 + q*4 + j, col = n0 + t*16 + r
#pragma unroll
    for (int t = 0; t < 5; ++t) {
        int n = n0 + t * 16 + r;
        if (n < 256) {
#pragma unroll
            for (int j = 0; j < 4; ++j)
                qk[(size_t)(m0 + q * 4 + j) * 256 + n] = acc[t][j];
        } else {
#pragma unroll
            for (int j = 0; j < 4; ++j)
                part[(size_t)(m0 + q * 4 + j) * NTYP + (n - 256)] = acc[t][j];
        }
    }
}

// ---------------- attention: one wave/query, writes final out ---------------
__global__ __launch_bounds__(256) void k_attn4b(const float* __restrict__ h_grp,
                                                const int* __restrict__ idx,
                                                const int* __restrict__ pos2grp,
                                                const int* __restrict__ msk,
                                                const float* __restrict__ zw,
                                                const float* __restrict__ qk,
                                                const float* __restrict__ part,
                                                const float* __restrict__ brel,
                                                float* __restrict__ out) {
    int bid = blockIdx.x;
    int swz = (bid & 7) * 256 + (bid >> 3);    // 2048 blocks, XCD-chunked
    int w = threadIdx.x >> 6;
    int lane = threadIdx.x & 63;
    int m = swz * 4 + w;
    int n = idx[m];
    int j = lane & 15;
    int gr = lane >> 4;

    const float4* qk4 = (const float4*)(qk + (size_t)m * 256);
    float4 qv0 = qk4[j];
    float4 qv1 = qk4[j + 16];
    float4 qv2 = qk4[j + 32];
    float4 qv3 = qk4[j + 48];

    const float* hbase = h_grp + (size_t)n * LL * DH + (size_t)gr * 16 * DH;
    float score = 0.f;
#pragma unroll
    for (int rr = 0; rr < 16; ++rr) {
        const float4* hr = (const float4*)(hbase + rr * DH);
        float4 h0 = hr[j];
        float4 h1 = hr[j + 16];
        float4 h2 = hr[j + 32];
        float4 h3 = hr[j + 48];
        float p = h0.x * qv0.x + h0.y * qv0.y + h0.z * qv0.z + h0.w * qv0.w
                + h1.x * qv1.x + h1.y * qv1.y + h1.z * qv1.z + h1.w * qv1.w
                + h2.x * qv2.x + h2.y * qv2.y + h2.z * qv2.z + h2.w * qv2.w
                + h3.x * qv3.x + h3.y * qv3.y + h3.z * qv3.z + h3.w * qv3.w;
        p += __shfl_xor(p, 1);
        p += __shfl_xor(p, 2);
        p += __shfl_xor(p, 4);
        p += __shfl_xor(p, 8);
        if (j == rr) score = p;
    }

    int mk = msk[n * LL + lane];
    int g  = pos2grp[n * LL + lane];
    float sv = mk ? score * (1.0f / 16.0f) : -INFINITY;
    float mx = sv;
    for (int o = 32; o; o >>= 1) mx = fmaxf(mx, __shfl_xor(mx, o));
    float p = mk ? __expf(sv - mx) : 0.f;
    float sum = p;
    for (int o = 32; o; o >>= 1) sum += __shfl_xor(sum, o);
    float attn = p / sum;

    float acc = part[(size_t)m * NTYP + lane] + brel[lane];
#pragma unroll 16
    for (int l = 0; l < 64; ++l) {
        float al = bcast(attn, l);
        int gl = __builtin_amdgcn_readlane(g, l);
        acc += al * zw[(size_t)gl * NTYP + lane];
    }
    out[(size_t)m * NTYP + lane] = acc;
}

extern "C" void kernel_launch(void* const* d_in, const int* in_sizes, int n_in,
                              void* d_out, int out_size, void* d_ws, size_t ws_size,
                              hipStream_t stream) {
    const int*   mem     = (const int*)d_in[0];
    const int*   grp     = (const int*)d_in[1];
    const int*   pos2grp = (const int*)d_in[2];
    const float* h_grp   = (const float*)d_in[3];
    const int*   msk     = (const int*)d_in[4];
    const int*   idx     = (const int*)d_in[5];
    const int*   srcv    = (const int*)d_in[6];
    const int*   dstv    = (const int*)d_in[7];
    // d_in[8] = typ (unused by the reference)
    const float* tok_emb = (const float*)d_in[9];
    const float* Wq      = (const float*)d_in[10];
    const float* bq      = (const float*)d_in[11];
    const float* Wk      = (const float*)d_in[12];
    const float* bk      = (const float*)d_in[13];  // softmax-invariant: unused
    const float* Wrel    = (const float*)d_in[14];
    const float* brel    = (const float*)d_in[15];
    float* out = (float*)d_out;
    (void)bk;

    float* ws = (float*)d_ws;
    size_t off = 0;
    float* zw   = ws + off; off += (size_t)GG * NTYP;       // 262144
    float* qk   = ws + off; off += (size_t)MQ * 256;        // 2097152
    float* part = ws + off; off += (size_t)MQ * NTYP;       // 524288
    float* bias = ws + off; off += 320;
    unsigned short* BT = (unsigned short*)(ws + off); off += (320 * 512) / 2; // 81920 floats
    int* cnt        = (int*)(ws + off); off += GG;
    int* ofs        = (int*)(ws + off); off += GG;
    int* cur        = (int*)(ws + off); off += GG;
    int* tok_sorted = (int*)(ws + off); off += NMEM;

    // segment-sum via counting sort (no float atomics), fused zw projection
    hipMemsetAsync(cnt, 0, GG * sizeof(int), stream);
    k_hist<<<NMEM / 256, 256, 0, stream>>>(grp, cnt);
    k_scan<<<1, 1024, 0, stream>>>(cnt, ofs, cur);
    k_permute<<<NMEM / 256, 256, 0, stream>>>(grp, mem, cur, tok_sorted);
    k_zsum<<<GG, 128, 0, stream>>>(ofs, cnt, tok_sorted, tok_emb, Wrel, zw);

    // folded weights -> bf16 B^T [320][512] + bias[320]
    k_wqkb<<<320, 256, 0, stream>>>(Wq, bq, Wk, Wrel, BT, bias);

    // MFMA GEMM: qk (256 cols) + logit partial (64 cols)
    k_gemm<<<MQ / 16, 256, 0, stream>>>(h_grp, idx, srcv, dstv, BT, bias, qk, part);

    // one wave per query, writes final out
    k_attn4b<<<2048, 256, 0, stream>>>(h_grp, idx, pos2grp, msk, zw, qk, part, brel, out);
}